// Round 6
// baseline (981.568 us; speedup 1.0000x reference)
//
#include <hip/hip_runtime.h>
#include <hip/hip_bf16.h>
#include <hip/hip_fp16.h>
#include <math.h>

#define NN 50000
#define NE 400000
#define INDIM 128
#define HID 64
#define HC 256
#define NL 6
#define ED 16
#define SCAN_B 256
#define SCAN_NB ((NN + SCAN_B - 1)/SCAN_B)   // 196

typedef __attribute__((ext_vector_type(8))) short short8;
typedef __attribute__((ext_vector_type(4))) float f32x4;
typedef _Float16 h2 __attribute__((ext_vector_type(2)));

static __device__ __forceinline__ float4 ld4(const float* p){ return *(const float4*)p; }
static __device__ __forceinline__ unsigned short f2b(float x){
  __hip_bfloat16 h = __float2bfloat16(x);
  return *(unsigned short*)&h;
}
static __device__ __forceinline__ unsigned short f2h(float x){
  __half h = __float2half(x);
  return *(unsigned short*)&h;
}
static __device__ __forceinline__ h2 bch2(unsigned int u){
  union{unsigned int i; h2 h;} v; v.i = u; return v.h;
}
static __device__ __forceinline__ h2 habs2(h2 x){
  union{h2 h; unsigned int i;} v; v.h = x; v.i &= 0x7FFF7FFFu; return v.h;
}

// ---------------- prep: bf16 weights + Wl/Wr fusion + ep_table ----------------
__global__ void prep_kernel(const float* __restrict__ inW, const float* __restrict__ Wl,
                            const float* __restrict__ Wr, const float* __restrict__ bl,
                            const float* __restrict__ br, const float* __restrict__ etab,
                            const float* __restrict__ We,
                            unsigned short* __restrict__ inW_bf,
                            unsigned short* __restrict__ Wlr,
                            float* __restrict__ blr, float* __restrict__ ep){
  int i = blockIdx.x*blockDim.x + threadIdx.x;
  if (i < HID*INDIM) inW_bf[i] = f2b(inW[i]);
  if (i < NL*512){
    int l = i / 512, c = i % 512;
    blr[i] = (c < HC) ? bl[l*HC + c] : br[l*HC + (c-HC)];
  }
  if (i < NL*3*HC){
    int l  = i / (3*HC);
    int a  = (i / HC) % 3;
    int hc = i % HC;
    const float* wrow = We + ((size_t)l*HC + hc)*ED;
    const float* erow = etab + a*ED;
    float s = 0.f;
    #pragma unroll
    for (int k=0;k<ED;k++) s += erow[k]*wrow[k];
    ep[i] = s;
  }
  int tot = NL*512*HID;
  for (int j = i; j < tot; j += gridDim.x*blockDim.x){
    int l = j / (512*HID);
    int c = (j / HID) % 512;
    int k = j % HID;
    float v = (c < HC) ? Wl[((size_t)l*HC + c)*HID + k]
                       : Wr[((size_t)l*HC + (c-HC))*HID + k];
    Wlr[j] = f2b(v);
  }
}

// ---------------- CSR build ----------------
__global__ void deg_kernel(const int* __restrict__ dst, int* __restrict__ deg){
  int e = blockIdx.x*blockDim.x + threadIdx.x;
  if (e < NE) atomicAdd(&deg[dst[e]], 1);
}

__global__ void scanA_kernel(const int* __restrict__ deg, int* __restrict__ bsum){
  int t = threadIdx.x;
  int i = blockIdx.x*SCAN_B + t;
  int v = (i < NN) ? deg[i] : 0;
  #pragma unroll
  for (int o=1;o<64;o<<=1) v += __shfl_xor(v,o);
  __shared__ int ws[4];
  if ((t&63)==0) ws[t>>6] = v;
  __syncthreads();
  if (t==0) bsum[blockIdx.x] = ws[0]+ws[1]+ws[2]+ws[3];
}

__global__ void scanB_kernel(int* __restrict__ bsum){
  __shared__ int sh[256];
  int t = threadIdx.x;
  int v = (t < SCAN_NB) ? bsum[t] : 0;
  sh[t] = v;
  __syncthreads();
  for (int o=1;o<256;o<<=1){
    int u = (t>=o)?sh[t-o]:0;
    __syncthreads();
    sh[t]+=u;
    __syncthreads();
  }
  int excl = (t==0)?0:sh[t-1];
  if (t < SCAN_NB) bsum[t] = excl;
}

__global__ void scanC_kernel(const int* __restrict__ deg, const int* __restrict__ bsum,
                             int* __restrict__ rowp){
  int t = threadIdx.x, b = blockIdx.x;
  int i = b*SCAN_B + t;
  int v = (i<NN)?deg[i]:0;
  __shared__ int sh[256];
  sh[t]=v;
  __syncthreads();
  for (int o=1;o<256;o<<=1){
    int u=(t>=o)?sh[t-o]:0;
    __syncthreads();
    sh[t]+=u;
    __syncthreads();
  }
  if (i < NN) rowp[i] = bsum[b] + sh[t] - v;
  if (i == 0) rowp[NN] = NE;
}

// scatter packed (src | attr<<16); consumes deg as a countdown counter
__global__ void scatter_kernel(const int* __restrict__ src, const int* __restrict__ dst,
                               const int* __restrict__ attr, const int* __restrict__ rowp,
                               int* __restrict__ deg, int* __restrict__ csrp){
  int e = blockIdx.x*blockDim.x + threadIdx.x;
  if (e >= NE) return;
  int d = dst[e];
  int pos = rowp[d] + atomicSub(&deg[d], 1) - 1;
  csrp[pos] = src[e] | (attr[e] << 16);
}

// ---------------- input GEMM: h = x @ inW.T + b ----------------
__global__ __launch_bounds__(256) void gemm_in_kernel(
    const float* __restrict__ X, const unsigned short* __restrict__ Wbf,
    const float* __restrict__ bias, float* __restrict__ hout, unsigned short* __restrict__ hbf)
{
  int wid = threadIdx.x >> 6, lane = threadIdx.x & 63;
  int row0 = blockIdx.x*128 + wid*32;
  int lr = lane & 15, lk = lane >> 4;
  short8 a[2][4];
  #pragma unroll
  for (int rt=0; rt<2; rt++){
    int r = row0 + rt*16 + lr; if (r >= NN) r = NN-1;
    const float* rp = X + (size_t)r*INDIM;
    #pragma unroll
    for (int ks=0; ks<4; ks++){
      const float* p = rp + ks*32 + lk*8;
      float4 u = ld4(p), v = ld4(p+4);
      short8 t;
      t[0]=(short)f2b(u.x); t[1]=(short)f2b(u.y); t[2]=(short)f2b(u.z); t[3]=(short)f2b(u.w);
      t[4]=(short)f2b(v.x); t[5]=(short)f2b(v.y); t[6]=(short)f2b(v.z); t[7]=(short)f2b(v.w);
      a[rt][ks] = t;
    }
  }
  f32x4 acc[2][4] = {};
  #pragma unroll
  for (int ct=0; ct<4; ct++){
    int c = ct*16 + lr;
    #pragma unroll
    for (int ks=0; ks<4; ks++){
      short8 b = *(const short8*)&Wbf[(size_t)c*INDIM + ks*32 + lk*8];
      #pragma unroll
      for (int rt=0; rt<2; rt++)
        acc[rt][ct] = __builtin_amdgcn_mfma_f32_16x16x32_bf16(a[rt][ks], b, acc[rt][ct], 0,0,0);
    }
  }
  #pragma unroll
  for (int rt=0; rt<2; rt++)
    #pragma unroll
    for (int ct=0; ct<4; ct++){
      int c = ct*16 + lr;
      float bv = bias[c];
      #pragma unroll
      for (int q=0;q<4;q++){
        int r = row0 + rt*16 + lk*4 + q;
        if (r < NN){
          float v = acc[rt][ct][q] + bv;
          hout[(size_t)r*HID + c] = v;
          hbf[(size_t)r*HID + c] = f2b(v);
        }
      }
    }
}

// ---------------- layer GEMM: xlr = h_bf @ Wlr.T + blr ([NN][512] fp16) ----------------
__global__ __launch_bounds__(256) void gemm_lr_kernel(
    const unsigned short* __restrict__ Abf, const unsigned short* __restrict__ Wbf,
    const float* __restrict__ bias, unsigned short* __restrict__ out)
{
  int wid = threadIdx.x >> 6, lane = threadIdx.x & 63;
  int row0 = blockIdx.x*128 + wid*32;
  int col0 = blockIdx.y*64;
  int lr = lane & 15, lk = lane >> 4;
  short8 a[2][2];
  #pragma unroll
  for (int rt=0; rt<2; rt++){
    int r = row0 + rt*16 + lr; if (r >= NN) r = NN-1;
    #pragma unroll
    for (int ks=0; ks<2; ks++)
      a[rt][ks] = *(const short8*)&Abf[(size_t)r*HID + ks*32 + lk*8];
  }
  f32x4 acc[2][4] = {};
  #pragma unroll
  for (int ct=0; ct<4; ct++){
    int c = col0 + ct*16 + lr;
    #pragma unroll
    for (int ks=0; ks<2; ks++){
      short8 b = *(const short8*)&Wbf[(size_t)c*HID + ks*32 + lk*8];
      #pragma unroll
      for (int rt=0; rt<2; rt++)
        acc[rt][ct] = __builtin_amdgcn_mfma_f32_16x16x32_bf16(a[rt][ks], b, acc[rt][ct], 0,0,0);
    }
  }
  #pragma unroll
  for (int rt=0; rt<2; rt++)
    #pragma unroll
    for (int ct=0; ct<4; ct++){
      int c = col0 + ct*16 + lr;
      float bv = bias[c];
      #pragma unroll
      for (int q=0;q<4;q++){
        int r = row0 + rt*16 + lk*4 + q;
        if (r < NN) out[(size_t)r*512 + c] = f2h(acc[rt][ct][q] + bv);
      }
    }
}

// ---------------- fused GATv2 aggregation + head-mean + LN + residual + relu ----------------
// one wave per dst node; lane holds 4 channels of [H=4][C=64]; xlr fp16 [NN][512]
// structure frozen at round-5 (2-wide unroll); per-edge math in packed fp16:
//   lrelu(m)·att = m·(0.6·att) + |m|·(0.4·att)  via v_dot2_f32_f16
//   att pre-scaled by log2(e) so p = exp2(part) is one v_exp_f32
//   xre[a] = xr + ep[a] hoisted per node (no per-edge ep load)
__global__ __launch_bounds__(256) void agg_kernel(
    const unsigned short* __restrict__ xlr,
    const int* __restrict__ rowp, const int* __restrict__ csrp,
    const float* __restrict__ ep_l, const float* __restrict__ att_l,
    const float* __restrict__ bias_l, const float* __restrict__ g_l, const float* __restrict__ b_l,
    const float* __restrict__ h_in, float* __restrict__ h_out, unsigned short* __restrict__ hbf,
    int use_res, int do_relu)
{
  int d = (blockIdx.x << 2) | (threadIdx.x >> 6);
  int lane = threadIdx.x & 63;
  if (d >= NN) return;
  int cb = lane << 2;

  uint2 xru = *(const uint2*)(xlr + ((size_t)d << 9) + 256 + cb);
  h2 xr2a = bch2(xru.x), xr2b = bch2(xru.y);
  float xrf0 = (float)xr2a.x, xrf1 = (float)xr2a.y;
  float xrf2 = (float)xr2b.x, xrf3 = (float)xr2b.y;

  float4 ev0 = ld4(ep_l + cb);
  float4 ev1 = ld4(ep_l + HC + cb);
  float4 ev2 = ld4(ep_l + 2*HC + cb);
  h2 xre0a = {(_Float16)(xrf0+ev0.x), (_Float16)(xrf1+ev0.y)};
  h2 xre0b = {(_Float16)(xrf2+ev0.z), (_Float16)(xrf3+ev0.w)};
  h2 xre1a = {(_Float16)(xrf0+ev1.x), (_Float16)(xrf1+ev1.y)};
  h2 xre1b = {(_Float16)(xrf2+ev1.z), (_Float16)(xrf3+ev1.w)};
  h2 xre2a = {(_Float16)(xrf0+ev2.x), (_Float16)(xrf1+ev2.y)};
  h2 xre2b = {(_Float16)(xrf2+ev2.z), (_Float16)(xrf3+ev2.w)};

  float4 av = ld4(att_l + cb);
  const float K6 = 0.6f*1.44269504f, K4 = 0.4f*1.44269504f;
  h2 av6a = {(_Float16)(av.x*K6), (_Float16)(av.y*K6)};
  h2 av6b = {(_Float16)(av.z*K6), (_Float16)(av.w*K6)};
  h2 av4a = {(_Float16)(av.x*K4), (_Float16)(av.y*K4)};
  h2 av4b = {(_Float16)(av.z*K4), (_Float16)(av.w*K4)};

  float den = 0.f;
  float ax=0.f, ay=0.f, az=0.f, aw=0.f;

  auto body = [&](uint2 u, int a){
    h2 x2a = bch2(u.x), x2b = bch2(u.y);
    h2 ra = (a==0) ? xre0a : ((a==1) ? xre1a : xre2a);
    h2 rb = (a==0) ? xre0b : ((a==1) ? xre1b : xre2b);
    h2 m2a = x2a + ra;
    h2 m2b = x2b + rb;
    float part = __builtin_amdgcn_fdot2(m2a, av6a, 0.f, false);
    part = __builtin_amdgcn_fdot2(m2b, av6b, part, false);
    part = __builtin_amdgcn_fdot2(habs2(m2a), av4a, part, false);
    part = __builtin_amdgcn_fdot2(habs2(m2b), av4b, part, false);
    part += __shfl_xor(part, 1);
    part += __shfl_xor(part, 2);
    part += __shfl_xor(part, 4);
    part += __shfl_xor(part, 8);
    float p = exp2f(part);     // att pre-scaled by log2e; softmax shift-invariant
    den += p;
    ax = fmaf(p, (float)x2a.x, ax);
    ay = fmaf(p, (float)x2a.y, ay);
    az = fmaf(p, (float)x2b.x, az);
    aw = fmaf(p, (float)x2b.y, aw);
  };

  int beg = rowp[d], stop = rowp[d+1];
  int i = beg;
  for (; i + 2 <= stop; i += 2){
    int p0 = csrp[i], p1 = csrp[i+1];
    uint2 u0 = *(const uint2*)(xlr + ((size_t)(p0 & 0xFFFF) << 9) + cb);
    uint2 u1 = *(const uint2*)(xlr + ((size_t)(p1 & 0xFFFF) << 9) + cb);
    body(u0, p0 >> 16);
    body(u1, p1 >> 16);
  }
  if (i < stop){
    int p0 = csrp[i];
    uint2 u0 = *(const uint2*)(xlr + ((size_t)(p0 & 0xFFFF) << 9) + cb);
    body(u0, p0 >> 16);
  }

  float inv = (den > 0.f) ? 1.f/den : 0.f;
  ax *= inv; ay *= inv; az *= inv; aw *= inv;

  ax += __shfl_xor(ax,16); ay += __shfl_xor(ay,16); az += __shfl_xor(az,16); aw += __shfl_xor(aw,16);
  ax += __shfl_xor(ax,32); ay += __shfl_xor(ay,32); az += __shfl_xor(az,32); aw += __shfl_xor(aw,32);

  int cc = (lane & 15) << 2;
  float4 bv = ld4(bias_l + cc);
  float h0 = ax*0.25f + bv.x;
  float h1 = ay*0.25f + bv.y;
  float h2v = az*0.25f + bv.z;
  float h3 = aw*0.25f + bv.w;

  float s1 = h0+h1+h2v+h3;
  float s2 = h0*h0 + h1*h1 + h2v*h2v + h3*h3;
  s1 += __shfl_xor(s1,1); s2 += __shfl_xor(s2,1);
  s1 += __shfl_xor(s1,2); s2 += __shfl_xor(s2,2);
  s1 += __shfl_xor(s1,4); s2 += __shfl_xor(s2,4);
  s1 += __shfl_xor(s1,8); s2 += __shfl_xor(s2,8);
  float mu  = s1 * (1.f/64.f);
  float var = fmaxf(s2*(1.f/64.f) - mu*mu, 0.f);
  float rstd = rsqrtf(var + 1e-5f);
  float4 gv  = ld4(g_l + cc);
  float4 bbv = ld4(b_l + cc);
  float r0 = (h0-mu)*rstd*gv.x + bbv.x;
  float r1 = (h1-mu)*rstd*gv.y + bbv.y;
  float r2 = (h2v-mu)*rstd*gv.z + bbv.z;
  float r3 = (h3-mu)*rstd*gv.w + bbv.w;
  if (use_res){
    float4 hv = ld4(h_in + (size_t)d*HID + cc);
    r0 += hv.x; r1 += hv.y; r2 += hv.z; r3 += hv.w;
  }
  if (do_relu){
    r0 = fmaxf(r0, 0.f); r1 = fmaxf(r1, 0.f);
    r2 = fmaxf(r2, 0.f); r3 = fmaxf(r3, 0.f);
  }
  if (lane < 16){
    float4 o = {r0, r1, r2, r3};
    *(float4*)(h_out + (size_t)d*HID + cc) = o;
    ushort4 obv = {f2b(r0), f2b(r1), f2b(r2), f2b(r3)};
    *(ushort4*)(hbf + (size_t)d*HID + cc) = obv;
  }
}

// ---------------- launch ----------------
extern "C" void kernel_launch(void* const* d_in, const int* in_sizes, int n_in,
                              void* d_out, int out_size, void* d_ws, size_t ws_size,
                              hipStream_t stream){
  const float* x    = (const float*)d_in[0];
  const int*   ei   = (const int*)d_in[1];
  const int*   ea   = (const int*)d_in[2];
  const float* inW  = (const float*)d_in[3];
  const float* inb  = (const float*)d_in[4];
  const float* etab = (const float*)d_in[5];
  const float* Wl   = (const float*)d_in[6];
  const float* bl   = (const float*)d_in[7];
  const float* Wr   = (const float*)d_in[8];
  const float* br   = (const float*)d_in[9];
  const float* We   = (const float*)d_in[10];
  const float* att  = (const float*)d_in[11];
  const float* ob   = (const float*)d_in[12];
  const float* lg   = (const float*)d_in[13];
  const float* lb   = (const float*)d_in[14];

  char* w = (char*)d_ws;
  size_t off = 0;
  auto alloc = [&](size_t bytes)->char*{
    char* p = w + off;
    off = (off + bytes + 255) & ~(size_t)255;
    return p;
  };
  float* hA    = (float*)alloc((size_t)NN*HID*4);
  float* hB    = (float*)alloc((size_t)NN*HID*4);
  unsigned short* hbf = (unsigned short*)alloc((size_t)NN*HID*2);
  unsigned short* xlr = (unsigned short*)alloc((size_t)NN*512*2);
  unsigned short* inW_bf = (unsigned short*)alloc((size_t)HID*INDIM*2);
  unsigned short* Wlr    = (unsigned short*)alloc((size_t)NL*512*HID*2);
  float* blr   = (float*)alloc((size_t)NL*512*4);
  float* ep    = (float*)alloc((size_t)NL*3*HC*4);
  int*   deg   = (int*)alloc((size_t)NN*4);
  int*   bsum  = (int*)alloc((size_t)SCAN_NB*4);
  int*   rowp  = (int*)alloc((size_t)(NN+1)*4);
  int*   csrp  = (int*)alloc((size_t)NE*4);

  hipMemsetAsync(deg, 0, (size_t)NN*4, stream);

  const int* srcp = ei;
  const int* dstp = ei + NE;
  deg_kernel<<<dim3((NE+255)/256), dim3(256), 0, stream>>>(dstp, deg);
  scanA_kernel<<<dim3(SCAN_NB), dim3(256), 0, stream>>>(deg, bsum);
  scanB_kernel<<<dim3(1), dim3(256), 0, stream>>>(bsum);
  scanC_kernel<<<dim3(SCAN_NB), dim3(256), 0, stream>>>(deg, bsum, rowp);
  scatter_kernel<<<dim3((NE+255)/256), dim3(256), 0, stream>>>(srcp, dstp, ea, rowp, deg, csrp);
  prep_kernel<<<dim3(64), dim3(256), 0, stream>>>(inW, Wl, Wr, bl, br, etab, We, inW_bf, Wlr, blr, ep);

  const int MB = (NN + 127)/128;   // 391
  gemm_in_kernel<<<dim3(MB), dim3(256), 0, stream>>>(x, inW_bf, inb, hA, hbf);

  float* hcur = hA; float* hnext = hB;
  for (int l=0; l<NL; l++){
    gemm_lr_kernel<<<dim3(MB,8), dim3(256), 0, stream>>>(
        hbf, Wlr + (size_t)l*512*HID, blr + (size_t)l*512, xlr);
    float* hout = (l == NL-1) ? (float*)d_out : hnext;
    agg_kernel<<<dim3((NN+3)/4), dim3(256), 0, stream>>>(
        xlr, rowp, csrp,
        ep + (size_t)l*3*HC, att + (size_t)l*HC,
        ob + (size_t)l*HID, lg + (size_t)l*HID, lb + (size_t)l*HID,
        hcur, hout, hbf, (l >= NL/2) ? 1 : 0, (l < NL-1) ? 1 : 0);
    float* t = hcur; hcur = hnext; hnext = t;
  }
}

// Round 7
// 587.483 us; speedup vs baseline: 1.6708x; 1.6708x over previous
//
#include <hip/hip_runtime.h>
#include <hip/hip_bf16.h>
#include <hip/hip_fp16.h>
#include <math.h>

#define NN 50000
#define NE 400000
#define INDIM 128
#define HID 64
#define HC 256
#define NL 6
#define ED 16
#define SCAN_B 256
#define SCAN_NB ((NN + SCAN_B - 1)/SCAN_B)   // 196

typedef __attribute__((ext_vector_type(8))) short short8;
typedef __attribute__((ext_vector_type(4))) float f32x4;
typedef _Float16 h2 __attribute__((ext_vector_type(2)));

static __device__ __forceinline__ float4 ld4(const float* p){ return *(const float4*)p; }
static __device__ __forceinline__ unsigned short f2b(float x){
  __hip_bfloat16 h = __float2bfloat16(x);
  return *(unsigned short*)&h;
}
static __device__ __forceinline__ unsigned short f2h(float x){
  __half h = __float2half(x);
  return *(unsigned short*)&h;
}

// ---------------- prep: bf16 weights + Wl/Wr fusion + ep_table ----------------
__global__ void prep_kernel(const float* __restrict__ inW, const float* __restrict__ Wl,
                            const float* __restrict__ Wr, const float* __restrict__ bl,
                            const float* __restrict__ br, const float* __restrict__ etab,
                            const float* __restrict__ We,
                            unsigned short* __restrict__ inW_bf,
                            unsigned short* __restrict__ Wlr,
                            float* __restrict__ blr, float* __restrict__ ep){
  int i = blockIdx.x*blockDim.x + threadIdx.x;
  if (i < HID*INDIM) inW_bf[i] = f2b(inW[i]);
  if (i < NL*512){
    int l = i / 512, c = i % 512;
    blr[i] = (c < HC) ? bl[l*HC + c] : br[l*HC + (c-HC)];
  }
  if (i < NL*3*HC){
    int l  = i / (3*HC);
    int a  = (i / HC) % 3;
    int hc = i % HC;
    const float* wrow = We + ((size_t)l*HC + hc)*ED;
    const float* erow = etab + a*ED;
    float s = 0.f;
    #pragma unroll
    for (int k=0;k<ED;k++) s += erow[k]*wrow[k];
    ep[i] = s;
  }
  int tot = NL*512*HID;
  for (int j = i; j < tot; j += gridDim.x*blockDim.x){
    int l = j / (512*HID);
    int c = (j / HID) % 512;
    int k = j % HID;
    float v = (c < HC) ? Wl[((size_t)l*HC + c)*HID + k]
                       : Wr[((size_t)l*HC + (c-HC))*HID + k];
    Wlr[j] = f2b(v);
  }
}

// ---------------- CSR build ----------------
__global__ void deg_kernel(const int* __restrict__ dst, int* __restrict__ deg){
  int e = blockIdx.x*blockDim.x + threadIdx.x;
  if (e < NE) atomicAdd(&deg[dst[e]], 1);
}

__global__ void scanA_kernel(const int* __restrict__ deg, int* __restrict__ bsum){
  int t = threadIdx.x;
  int i = blockIdx.x*SCAN_B + t;
  int v = (i < NN) ? deg[i] : 0;
  #pragma unroll
  for (int o=1;o<64;o<<=1) v += __shfl_xor(v,o);
  __shared__ int ws[4];
  if ((t&63)==0) ws[t>>6] = v;
  __syncthreads();
  if (t==0) bsum[blockIdx.x] = ws[0]+ws[1]+ws[2]+ws[3];
}

__global__ void scanB_kernel(int* __restrict__ bsum){
  __shared__ int sh[256];
  int t = threadIdx.x;
  int v = (t < SCAN_NB) ? bsum[t] : 0;
  sh[t] = v;
  __syncthreads();
  for (int o=1;o<256;o<<=1){
    int u = (t>=o)?sh[t-o]:0;
    __syncthreads();
    sh[t]+=u;
    __syncthreads();
  }
  int excl = (t==0)?0:sh[t-1];
  if (t < SCAN_NB) bsum[t] = excl;
}

__global__ void scanC_kernel(const int* __restrict__ deg, const int* __restrict__ bsum,
                             int* __restrict__ rowp){
  int t = threadIdx.x, b = blockIdx.x;
  int i = b*SCAN_B + t;
  int v = (i<NN)?deg[i]:0;
  __shared__ int sh[256];
  sh[t]=v;
  __syncthreads();
  for (int o=1;o<256;o<<=1){
    int u=(t>=o)?sh[t-o]:0;
    __syncthreads();
    sh[t]+=u;
    __syncthreads();
  }
  if (i < NN) rowp[i] = bsum[b] + sh[t] - v;
  if (i == 0) rowp[NN] = NE;
}

// scatter packed (src | attr<<16); consumes deg as a countdown counter
__global__ void scatter_kernel(const int* __restrict__ src, const int* __restrict__ dst,
                               const int* __restrict__ attr, const int* __restrict__ rowp,
                               int* __restrict__ deg, int* __restrict__ csrp){
  int e = blockIdx.x*blockDim.x + threadIdx.x;
  if (e >= NE) return;
  int d = dst[e];
  int pos = rowp[d] + atomicSub(&deg[d], 1) - 1;
  csrp[pos] = src[e] | (attr[e] << 16);
}

// ---------------- input GEMM: h = x @ inW.T + b ----------------
__global__ __launch_bounds__(256) void gemm_in_kernel(
    const float* __restrict__ X, const unsigned short* __restrict__ Wbf,
    const float* __restrict__ bias, float* __restrict__ hout, unsigned short* __restrict__ hbf)
{
  int wid = threadIdx.x >> 6, lane = threadIdx.x & 63;
  int row0 = blockIdx.x*128 + wid*32;
  int lr = lane & 15, lk = lane >> 4;
  short8 a[2][4];
  #pragma unroll
  for (int rt=0; rt<2; rt++){
    int r = row0 + rt*16 + lr; if (r >= NN) r = NN-1;
    const float* rp = X + (size_t)r*INDIM;
    #pragma unroll
    for (int ks=0; ks<4; ks++){
      const float* p = rp + ks*32 + lk*8;
      float4 u = ld4(p), v = ld4(p+4);
      short8 t;
      t[0]=(short)f2b(u.x); t[1]=(short)f2b(u.y); t[2]=(short)f2b(u.z); t[3]=(short)f2b(u.w);
      t[4]=(short)f2b(v.x); t[5]=(short)f2b(v.y); t[6]=(short)f2b(v.z); t[7]=(short)f2b(v.w);
      a[rt][ks] = t;
    }
  }
  f32x4 acc[2][4] = {};
  #pragma unroll
  for (int ct=0; ct<4; ct++){
    int c = ct*16 + lr;
    #pragma unroll
    for (int ks=0; ks<4; ks++){
      short8 b = *(const short8*)&Wbf[(size_t)c*INDIM + ks*32 + lk*8];
      #pragma unroll
      for (int rt=0; rt<2; rt++)
        acc[rt][ct] = __builtin_amdgcn_mfma_f32_16x16x32_bf16(a[rt][ks], b, acc[rt][ct], 0,0,0);
    }
  }
  #pragma unroll
  for (int rt=0; rt<2; rt++)
    #pragma unroll
    for (int ct=0; ct<4; ct++){
      int c = ct*16 + lr;
      float bv = bias[c];
      #pragma unroll
      for (int q=0;q<4;q++){
        int r = row0 + rt*16 + lk*4 + q;
        if (r < NN){
          float v = acc[rt][ct][q] + bv;
          hout[(size_t)r*HID + c] = v;
          hbf[(size_t)r*HID + c] = f2b(v);
        }
      }
    }
}

// ---------------- layer GEMM: xlr = h_bf @ Wlr.T + blr ([NN][512] fp16) ----------------
__global__ __launch_bounds__(256) void gemm_lr_kernel(
    const unsigned short* __restrict__ Abf, const unsigned short* __restrict__ Wbf,
    const float* __restrict__ bias, unsigned short* __restrict__ out)
{
  int wid = threadIdx.x >> 6, lane = threadIdx.x & 63;
  int row0 = blockIdx.x*128 + wid*32;
  int col0 = blockIdx.y*64;
  int lr = lane & 15, lk = lane >> 4;
  short8 a[2][2];
  #pragma unroll
  for (int rt=0; rt<2; rt++){
    int r = row0 + rt*16 + lr; if (r >= NN) r = NN-1;
    #pragma unroll
    for (int ks=0; ks<2; ks++)
      a[rt][ks] = *(const short8*)&Abf[(size_t)r*HID + ks*32 + lk*8];
  }
  f32x4 acc[2][4] = {};
  #pragma unroll
  for (int ct=0; ct<4; ct++){
    int c = col0 + ct*16 + lr;
    #pragma unroll
    for (int ks=0; ks<2; ks++){
      short8 b = *(const short8*)&Wbf[(size_t)c*HID + ks*32 + lk*8];
      #pragma unroll
      for (int rt=0; rt<2; rt++)
        acc[rt][ct] = __builtin_amdgcn_mfma_f32_16x16x32_bf16(a[rt][ks], b, acc[rt][ct], 0,0,0);
    }
  }
  #pragma unroll
  for (int rt=0; rt<2; rt++)
    #pragma unroll
    for (int ct=0; ct<4; ct++){
      int c = col0 + ct*16 + lr;
      float bv = bias[c];
      #pragma unroll
      for (int q=0;q<4;q++){
        int r = row0 + rt*16 + lk*4 + q;
        if (r < NN) out[(size_t)r*512 + c] = f2h(acc[rt][ct][q] + bv);
      }
    }
}

// ---------------- fused GATv2 aggregation + head-mean + LN + residual + relu ----------------
// one wave per dst node; lane holds 4 channels of [H=4][C=64]; xlr fp16 [NN][512]
// VALU-diet edge math (straight-line, no lambda/union -> no scratch):
//   lrelu(m)·att = m·(0.6·att) + |m|·(0.4·att) via v_dot2_f32_f16
//   att pre-scaled by log2(e): p = exp2(part)
//   xre[a] = xr + ep[a] hoisted per node
#define EDGE_BODY(UX, UY, A)                                                   \
  {                                                                            \
    h2 x2a = __builtin_bit_cast(h2, (UX));                                     \
    h2 x2b = __builtin_bit_cast(h2, (UY));                                     \
    h2 m2a = x2a + ((A)==0 ? xre0a : ((A)==1 ? xre1a : xre2a));                \
    h2 m2b = x2b + ((A)==0 ? xre0b : ((A)==1 ? xre1b : xre2b));                \
    h2 n2a = __builtin_bit_cast(h2, __builtin_bit_cast(unsigned, m2a) & 0x7FFF7FFFu); \
    h2 n2b = __builtin_bit_cast(h2, __builtin_bit_cast(unsigned, m2b) & 0x7FFF7FFFu); \
    float part = __builtin_amdgcn_fdot2(m2a, av6a, 0.f, false);                \
    part = __builtin_amdgcn_fdot2(m2b, av6b, part, false);                     \
    part = __builtin_amdgcn_fdot2(n2a, av4a, part, false);                     \
    part = __builtin_amdgcn_fdot2(n2b, av4b, part, false);                     \
    part += __shfl_xor(part, 1);                                               \
    part += __shfl_xor(part, 2);                                               \
    part += __shfl_xor(part, 4);                                               \
    part += __shfl_xor(part, 8);                                               \
    float p = exp2f(part);                                                     \
    den += p;                                                                  \
    ax = fmaf(p, (float)x2a.x, ax);                                            \
    ay = fmaf(p, (float)x2a.y, ay);                                            \
    az = fmaf(p, (float)x2b.x, az);                                            \
    aw = fmaf(p, (float)x2b.y, aw);                                            \
  }

__global__ __launch_bounds__(256) void agg_kernel(
    const unsigned short* __restrict__ xlr,
    const int* __restrict__ rowp, const int* __restrict__ csrp,
    const float* __restrict__ ep_l, const float* __restrict__ att_l,
    const float* __restrict__ bias_l, const float* __restrict__ g_l, const float* __restrict__ b_l,
    const float* __restrict__ h_in, float* __restrict__ h_out, unsigned short* __restrict__ hbf,
    int use_res, int do_relu)
{
  int d = (blockIdx.x << 2) | (threadIdx.x >> 6);
  int lane = threadIdx.x & 63;
  if (d >= NN) return;
  int cb = lane << 2;

  uint2 xru = *(const uint2*)(xlr + ((size_t)d << 9) + 256 + cb);
  h2 xr2a = __builtin_bit_cast(h2, xru.x);
  h2 xr2b = __builtin_bit_cast(h2, xru.y);
  float xrf0 = (float)xr2a.x, xrf1 = (float)xr2a.y;
  float xrf2 = (float)xr2b.x, xrf3 = (float)xr2b.y;

  float4 ev0 = ld4(ep_l + cb);
  float4 ev1 = ld4(ep_l + HC + cb);
  float4 ev2 = ld4(ep_l + 2*HC + cb);
  h2 xre0a = {(_Float16)(xrf0+ev0.x), (_Float16)(xrf1+ev0.y)};
  h2 xre0b = {(_Float16)(xrf2+ev0.z), (_Float16)(xrf3+ev0.w)};
  h2 xre1a = {(_Float16)(xrf0+ev1.x), (_Float16)(xrf1+ev1.y)};
  h2 xre1b = {(_Float16)(xrf2+ev1.z), (_Float16)(xrf3+ev1.w)};
  h2 xre2a = {(_Float16)(xrf0+ev2.x), (_Float16)(xrf1+ev2.y)};
  h2 xre2b = {(_Float16)(xrf2+ev2.z), (_Float16)(xrf3+ev2.w)};

  float4 av = ld4(att_l + cb);
  const float K6 = 0.6f*1.44269504f, K4 = 0.4f*1.44269504f;
  h2 av6a = {(_Float16)(av.x*K6), (_Float16)(av.y*K6)};
  h2 av6b = {(_Float16)(av.z*K6), (_Float16)(av.w*K6)};
  h2 av4a = {(_Float16)(av.x*K4), (_Float16)(av.y*K4)};
  h2 av4b = {(_Float16)(av.z*K4), (_Float16)(av.w*K4)};

  float den = 0.f;
  float ax=0.f, ay=0.f, az=0.f, aw=0.f;

  int beg = rowp[d], stop = rowp[d+1];
  int i = beg;
  for (; i + 2 <= stop; i += 2){
    int p0 = csrp[i], p1 = csrp[i+1];
    uint2 u0 = *(const uint2*)(xlr + ((size_t)(p0 & 0xFFFF) << 9) + cb);
    uint2 u1 = *(const uint2*)(xlr + ((size_t)(p1 & 0xFFFF) << 9) + cb);
    int a0 = p0 >> 16, a1 = p1 >> 16;
    EDGE_BODY(u0.x, u0.y, a0);
    EDGE_BODY(u1.x, u1.y, a1);
  }
  if (i < stop){
    int p0 = csrp[i];
    uint2 u0 = *(const uint2*)(xlr + ((size_t)(p0 & 0xFFFF) << 9) + cb);
    int a0 = p0 >> 16;
    EDGE_BODY(u0.x, u0.y, a0);
  }

  float inv = (den > 0.f) ? 1.f/den : 0.f;
  ax *= inv; ay *= inv; az *= inv; aw *= inv;

  ax += __shfl_xor(ax,16); ay += __shfl_xor(ay,16); az += __shfl_xor(az,16); aw += __shfl_xor(aw,16);
  ax += __shfl_xor(ax,32); ay += __shfl_xor(ay,32); az += __shfl_xor(az,32); aw += __shfl_xor(aw,32);

  int cc = (lane & 15) << 2;
  float4 bv = ld4(bias_l + cc);
  float h0 = ax*0.25f + bv.x;
  float h1 = ay*0.25f + bv.y;
  float h2v = az*0.25f + bv.z;
  float h3 = aw*0.25f + bv.w;

  float s1 = h0+h1+h2v+h3;
  float s2 = h0*h0 + h1*h1 + h2v*h2v + h3*h3;
  s1 += __shfl_xor(s1,1); s2 += __shfl_xor(s2,1);
  s1 += __shfl_xor(s1,2); s2 += __shfl_xor(s2,2);
  s1 += __shfl_xor(s1,4); s2 += __shfl_xor(s2,4);
  s1 += __shfl_xor(s1,8); s2 += __shfl_xor(s2,8);
  float mu  = s1 * (1.f/64.f);
  float var = fmaxf(s2*(1.f/64.f) - mu*mu, 0.f);
  float rstd = rsqrtf(var + 1e-5f);
  float4 gv  = ld4(g_l + cc);
  float4 bbv = ld4(b_l + cc);
  float r0 = (h0-mu)*rstd*gv.x + bbv.x;
  float r1 = (h1-mu)*rstd*gv.y + bbv.y;
  float r2 = (h2v-mu)*rstd*gv.z + bbv.z;
  float r3 = (h3-mu)*rstd*gv.w + bbv.w;
  if (use_res){
    float4 hv = ld4(h_in + (size_t)d*HID + cc);
    r0 += hv.x; r1 += hv.y; r2 += hv.z; r3 += hv.w;
  }
  if (do_relu){
    r0 = fmaxf(r0, 0.f); r1 = fmaxf(r1, 0.f);
    r2 = fmaxf(r2, 0.f); r3 = fmaxf(r3, 0.f);
  }
  if (lane < 16){
    float4 o = {r0, r1, r2, r3};
    *(float4*)(h_out + (size_t)d*HID + cc) = o;
    ushort4 obv = {f2b(r0), f2b(r1), f2b(r2), f2b(r3)};
    *(ushort4*)(hbf + (size_t)d*HID + cc) = obv;
  }
}

// ---------------- launch ----------------
extern "C" void kernel_launch(void* const* d_in, const int* in_sizes, int n_in,
                              void* d_out, int out_size, void* d_ws, size_t ws_size,
                              hipStream_t stream){
  const float* x    = (const float*)d_in[0];
  const int*   ei   = (const int*)d_in[1];
  const int*   ea   = (const int*)d_in[2];
  const float* inW  = (const float*)d_in[3];
  const float* inb  = (const float*)d_in[4];
  const float* etab = (const float*)d_in[5];
  const float* Wl   = (const float*)d_in[6];
  const float* bl   = (const float*)d_in[7];
  const float* Wr   = (const float*)d_in[8];
  const float* br   = (const float*)d_in[9];
  const float* We   = (const float*)d_in[10];
  const float* att  = (const float*)d_in[11];
  const float* ob   = (const float*)d_in[12];
  const float* lg   = (const float*)d_in[13];
  const float* lb   = (const float*)d_in[14];

  char* w = (char*)d_ws;
  size_t off = 0;
  auto alloc = [&](size_t bytes)->char*{
    char* p = w + off;
    off = (off + bytes + 255) & ~(size_t)255;
    return p;
  };
  float* hA    = (float*)alloc((size_t)NN*HID*4);
  float* hB    = (float*)alloc((size_t)NN*HID*4);
  unsigned short* hbf = (unsigned short*)alloc((size_t)NN*HID*2);
  unsigned short* xlr = (unsigned short*)alloc((size_t)NN*512*2);
  unsigned short* inW_bf = (unsigned short*)alloc((size_t)HID*INDIM*2);
  unsigned short* Wlr    = (unsigned short*)alloc((size_t)NL*512*HID*2);
  float* blr   = (float*)alloc((size_t)NL*512*4);
  float* ep    = (float*)alloc((size_t)NL*3*HC*4);
  int*   deg   = (int*)alloc((size_t)NN*4);
  int*   bsum  = (int*)alloc((size_t)SCAN_NB*4);
  int*   rowp  = (int*)alloc((size_t)(NN+1)*4);
  int*   csrp  = (int*)alloc((size_t)NE*4);

  hipMemsetAsync(deg, 0, (size_t)NN*4, stream);

  const int* srcp = ei;
  const int* dstp = ei + NE;
  deg_kernel<<<dim3((NE+255)/256), dim3(256), 0, stream>>>(dstp, deg);
  scanA_kernel<<<dim3(SCAN_NB), dim3(256), 0, stream>>>(deg, bsum);
  scanB_kernel<<<dim3(1), dim3(256), 0, stream>>>(bsum);
  scanC_kernel<<<dim3(SCAN_NB), dim3(256), 0, stream>>>(deg, bsum, rowp);
  scatter_kernel<<<dim3((NE+255)/256), dim3(256), 0, stream>>>(srcp, dstp, ea, rowp, deg, csrp);
  prep_kernel<<<dim3(64), dim3(256), 0, stream>>>(inW, Wl, Wr, bl, br, etab, We, inW_bf, Wlr, blr, ep);

  const int MB = (NN + 127)/128;   // 391
  gemm_in_kernel<<<dim3(MB), dim3(256), 0, stream>>>(x, inW_bf, inb, hA, hbf);

  float* hcur = hA; float* hnext = hB;
  for (int l=0; l<NL; l++){
    gemm_lr_kernel<<<dim3(MB,8), dim3(256), 0, stream>>>(
        hbf, Wlr + (size_t)l*512*HID, blr + (size_t)l*512, xlr);
    float* hout = (l == NL-1) ? (float*)d_out : hnext;
    agg_kernel<<<dim3((NN+3)/4), dim3(256), 0, stream>>>(
        xlr, rowp, csrp,
        ep + (size_t)l*3*HC, att + (size_t)l*HC,
        ob + (size_t)l*HID, lg + (size_t)l*HID, lb + (size_t)l*HID,
        hcur, hout, hbf, (l >= NL/2) ? 1 : 0, (l < NL-1) ? 1 : 0);
    float* t = hcur; hcur = hnext; hnext = t;
  }
}

// Round 8
// 557.526 us; speedup vs baseline: 1.7606x; 1.0537x over previous
//
#include <hip/hip_runtime.h>
#include <hip/hip_bf16.h>
#include <hip/hip_fp16.h>
#include <math.h>

#define NN 50000
#define NE 400000
#define INDIM 128
#define HID 64
#define HC 256
#define NL 6
#define ED 16
#define SCAN_B 256
#define SCAN_NB ((NN + SCAN_B - 1)/SCAN_B)   // 196

typedef __attribute__((ext_vector_type(8))) short short8;
typedef __attribute__((ext_vector_type(4))) float f32x4;
typedef _Float16 h2 __attribute__((ext_vector_type(2)));

static __device__ __forceinline__ float4 ld4(const float* p){ return *(const float4*)p; }
static __device__ __forceinline__ unsigned short f2b(float x){
  __hip_bfloat16 h = __float2bfloat16(x);
  return *(unsigned short*)&h;
}
static __device__ __forceinline__ unsigned short f2h(float x){
  __half h = __float2half(x);
  return *(unsigned short*)&h;
}

// ---------------- prep: bf16 weights + Wl/Wr fusion + ep_table ----------------
__global__ void prep_kernel(const float* __restrict__ inW, const float* __restrict__ Wl,
                            const float* __restrict__ Wr, const float* __restrict__ bl,
                            const float* __restrict__ br, const float* __restrict__ etab,
                            const float* __restrict__ We,
                            unsigned short* __restrict__ inW_bf,
                            unsigned short* __restrict__ Wlr,
                            float* __restrict__ blr, float* __restrict__ ep){
  int i = blockIdx.x*blockDim.x + threadIdx.x;
  if (i < HID*INDIM) inW_bf[i] = f2b(inW[i]);
  if (i < NL*512){
    int l = i / 512, c = i % 512;
    blr[i] = (c < HC) ? bl[l*HC + c] : br[l*HC + (c-HC)];
  }
  if (i < NL*3*HC){
    int l  = i / (3*HC);
    int a  = (i / HC) % 3;
    int hc = i % HC;
    const float* wrow = We + ((size_t)l*HC + hc)*ED;
    const float* erow = etab + a*ED;
    float s = 0.f;
    #pragma unroll
    for (int k=0;k<ED;k++) s += erow[k]*wrow[k];
    ep[i] = s;
  }
  int tot = NL*512*HID;
  for (int j = i; j < tot; j += gridDim.x*blockDim.x){
    int l = j / (512*HID);
    int c = (j / HID) % 512;
    int k = j % HID;
    float v = (c < HC) ? Wl[((size_t)l*HC + c)*HID + k]
                       : Wr[((size_t)l*HC + (c-HC))*HID + k];
    Wlr[j] = f2b(v);
  }
}

// ---------------- CSR build ----------------
__global__ void deg_kernel(const int* __restrict__ dst, int* __restrict__ deg){
  int e = blockIdx.x*blockDim.x + threadIdx.x;
  if (e < NE) atomicAdd(&deg[dst[e]], 1);
}

__global__ void scanA_kernel(const int* __restrict__ deg, int* __restrict__ bsum){
  int t = threadIdx.x;
  int i = blockIdx.x*SCAN_B + t;
  int v = (i < NN) ? deg[i] : 0;
  #pragma unroll
  for (int o=1;o<64;o<<=1) v += __shfl_xor(v,o);
  __shared__ int ws[4];
  if ((t&63)==0) ws[t>>6] = v;
  __syncthreads();
  if (t==0) bsum[blockIdx.x] = ws[0]+ws[1]+ws[2]+ws[3];
}

__global__ void scanB_kernel(int* __restrict__ bsum){
  __shared__ int sh[256];
  int t = threadIdx.x;
  int v = (t < SCAN_NB) ? bsum[t] : 0;
  sh[t] = v;
  __syncthreads();
  for (int o=1;o<256;o<<=1){
    int u = (t>=o)?sh[t-o]:0;
    __syncthreads();
    sh[t]+=u;
    __syncthreads();
  }
  int excl = (t==0)?0:sh[t-1];
  if (t < SCAN_NB) bsum[t] = excl;
}

__global__ void scanC_kernel(const int* __restrict__ deg, const int* __restrict__ bsum,
                             int* __restrict__ rowp){
  int t = threadIdx.x, b = blockIdx.x;
  int i = b*SCAN_B + t;
  int v = (i<NN)?deg[i]:0;
  __shared__ int sh[256];
  sh[t]=v;
  __syncthreads();
  for (int o=1;o<256;o<<=1){
    int u=(t>=o)?sh[t-o]:0;
    __syncthreads();
    sh[t]+=u;
    __syncthreads();
  }
  if (i < NN) rowp[i] = bsum[b] + sh[t] - v;
  if (i == 0) rowp[NN] = NE;
}

// scatter packed (src | attr<<16); consumes deg as a countdown counter
__global__ void scatter_kernel(const int* __restrict__ src, const int* __restrict__ dst,
                               const int* __restrict__ attr, const int* __restrict__ rowp,
                               int* __restrict__ deg, int* __restrict__ csrp){
  int e = blockIdx.x*blockDim.x + threadIdx.x;
  if (e >= NE) return;
  int d = dst[e];
  int pos = rowp[d] + atomicSub(&deg[d], 1) - 1;
  csrp[pos] = src[e] | (attr[e] << 16);
}

// ---------------- input GEMM: h = x @ inW.T + b ----------------
__global__ __launch_bounds__(256) void gemm_in_kernel(
    const float* __restrict__ X, const unsigned short* __restrict__ Wbf,
    const float* __restrict__ bias, float* __restrict__ hout, unsigned short* __restrict__ hbf)
{
  int wid = threadIdx.x >> 6, lane = threadIdx.x & 63;
  int row0 = blockIdx.x*128 + wid*32;
  int lr = lane & 15, lk = lane >> 4;
  short8 a[2][4];
  #pragma unroll
  for (int rt=0; rt<2; rt++){
    int r = row0 + rt*16 + lr; if (r >= NN) r = NN-1;
    const float* rp = X + (size_t)r*INDIM;
    #pragma unroll
    for (int ks=0; ks<4; ks++){
      const float* p = rp + ks*32 + lk*8;
      float4 u = ld4(p), v = ld4(p+4);
      short8 t;
      t[0]=(short)f2b(u.x); t[1]=(short)f2b(u.y); t[2]=(short)f2b(u.z); t[3]=(short)f2b(u.w);
      t[4]=(short)f2b(v.x); t[5]=(short)f2b(v.y); t[6]=(short)f2b(v.z); t[7]=(short)f2b(v.w);
      a[rt][ks] = t;
    }
  }
  f32x4 acc[2][4] = {};
  #pragma unroll
  for (int ct=0; ct<4; ct++){
    int c = ct*16 + lr;
    #pragma unroll
    for (int ks=0; ks<4; ks++){
      short8 b = *(const short8*)&Wbf[(size_t)c*INDIM + ks*32 + lk*8];
      #pragma unroll
      for (int rt=0; rt<2; rt++)
        acc[rt][ct] = __builtin_amdgcn_mfma_f32_16x16x32_bf16(a[rt][ks], b, acc[rt][ct], 0,0,0);
    }
  }
  #pragma unroll
  for (int rt=0; rt<2; rt++)
    #pragma unroll
    for (int ct=0; ct<4; ct++){
      int c = ct*16 + lr;
      float bv = bias[c];
      #pragma unroll
      for (int q=0;q<4;q++){
        int r = row0 + rt*16 + lk*4 + q;
        if (r < NN){
          float v = acc[rt][ct][q] + bv;
          hout[(size_t)r*HID + c] = v;
          hbf[(size_t)r*HID + c] = f2b(v);
        }
      }
    }
}

// ---------------- layer GEMM: xlr = h_bf @ Wlr.T + blr ([NN][512] fp16) ----------------
__global__ __launch_bounds__(256) void gemm_lr_kernel(
    const unsigned short* __restrict__ Abf, const unsigned short* __restrict__ Wbf,
    const float* __restrict__ bias, unsigned short* __restrict__ out)
{
  int wid = threadIdx.x >> 6, lane = threadIdx.x & 63;
  int row0 = blockIdx.x*128 + wid*32;
  int col0 = blockIdx.y*64;
  int lr = lane & 15, lk = lane >> 4;
  short8 a[2][2];
  #pragma unroll
  for (int rt=0; rt<2; rt++){
    int r = row0 + rt*16 + lr; if (r >= NN) r = NN-1;
    #pragma unroll
    for (int ks=0; ks<2; ks++)
      a[rt][ks] = *(const short8*)&Abf[(size_t)r*HID + ks*32 + lk*8];
  }
  f32x4 acc[2][4] = {};
  #pragma unroll
  for (int ct=0; ct<4; ct++){
    int c = col0 + ct*16 + lr;
    #pragma unroll
    for (int ks=0; ks<2; ks++){
      short8 b = *(const short8*)&Wbf[(size_t)c*HID + ks*32 + lk*8];
      #pragma unroll
      for (int rt=0; rt<2; rt++)
        acc[rt][ct] = __builtin_amdgcn_mfma_f32_16x16x32_bf16(a[rt][ks], b, acc[rt][ct], 0,0,0);
    }
  }
  #pragma unroll
  for (int rt=0; rt<2; rt++)
    #pragma unroll
    for (int ct=0; ct<4; ct++){
      int c = col0 + ct*16 + lr;
      float bv = bias[c];
      #pragma unroll
      for (int q=0;q<4;q++){
        int r = row0 + rt*16 + lk*4 + q;
        if (r < NN) out[(size_t)r*512 + c] = f2h(acc[rt][ct][q] + bv);
      }
    }
}

// ---------------- fused GATv2 aggregation + head-mean + LN + residual + relu ----------------
// one wave per dst node; lane holds 4 channels of [H=4][C=64]; xlr fp16 [NN][512]
// round-8: identical edge math to round 7; main loop unrolled 4-wide (4 gathers in flight)
#define EDGE_BODY(UX, UY, A)                                                   \
  {                                                                            \
    h2 x2a = __builtin_bit_cast(h2, (UX));                                     \
    h2 x2b = __builtin_bit_cast(h2, (UY));                                     \
    h2 m2a = x2a + ((A)==0 ? xre0a : ((A)==1 ? xre1a : xre2a));                \
    h2 m2b = x2b + ((A)==0 ? xre0b : ((A)==1 ? xre1b : xre2b));                \
    h2 n2a = __builtin_bit_cast(h2, __builtin_bit_cast(unsigned, m2a) & 0x7FFF7FFFu); \
    h2 n2b = __builtin_bit_cast(h2, __builtin_bit_cast(unsigned, m2b) & 0x7FFF7FFFu); \
    float part = __builtin_amdgcn_fdot2(m2a, av6a, 0.f, false);                \
    part = __builtin_amdgcn_fdot2(m2b, av6b, part, false);                     \
    part = __builtin_amdgcn_fdot2(n2a, av4a, part, false);                     \
    part = __builtin_amdgcn_fdot2(n2b, av4b, part, false);                     \
    part += __shfl_xor(part, 1);                                               \
    part += __shfl_xor(part, 2);                                               \
    part += __shfl_xor(part, 4);                                               \
    part += __shfl_xor(part, 8);                                               \
    float p = exp2f(part);                                                     \
    den += p;                                                                  \
    ax = fmaf(p, (float)x2a.x, ax);                                            \
    ay = fmaf(p, (float)x2a.y, ay);                                            \
    az = fmaf(p, (float)x2b.x, az);                                            \
    aw = fmaf(p, (float)x2b.y, aw);                                            \
  }

__global__ __launch_bounds__(256) void agg_kernel(
    const unsigned short* __restrict__ xlr,
    const int* __restrict__ rowp, const int* __restrict__ csrp,
    const float* __restrict__ ep_l, const float* __restrict__ att_l,
    const float* __restrict__ bias_l, const float* __restrict__ g_l, const float* __restrict__ b_l,
    const float* __restrict__ h_in, float* __restrict__ h_out, unsigned short* __restrict__ hbf,
    int use_res, int do_relu)
{
  int d = (blockIdx.x << 2) | (threadIdx.x >> 6);
  int lane = threadIdx.x & 63;
  if (d >= NN) return;
  int cb = lane << 2;

  uint2 xru = *(const uint2*)(xlr + ((size_t)d << 9) + 256 + cb);
  h2 xr2a = __builtin_bit_cast(h2, xru.x);
  h2 xr2b = __builtin_bit_cast(h2, xru.y);
  float xrf0 = (float)xr2a.x, xrf1 = (float)xr2a.y;
  float xrf2 = (float)xr2b.x, xrf3 = (float)xr2b.y;

  float4 ev0 = ld4(ep_l + cb);
  float4 ev1 = ld4(ep_l + HC + cb);
  float4 ev2 = ld4(ep_l + 2*HC + cb);
  h2 xre0a = {(_Float16)(xrf0+ev0.x), (_Float16)(xrf1+ev0.y)};
  h2 xre0b = {(_Float16)(xrf2+ev0.z), (_Float16)(xrf3+ev0.w)};
  h2 xre1a = {(_Float16)(xrf0+ev1.x), (_Float16)(xrf1+ev1.y)};
  h2 xre1b = {(_Float16)(xrf2+ev1.z), (_Float16)(xrf3+ev1.w)};
  h2 xre2a = {(_Float16)(xrf0+ev2.x), (_Float16)(xrf1+ev2.y)};
  h2 xre2b = {(_Float16)(xrf2+ev2.z), (_Float16)(xrf3+ev2.w)};

  float4 av = ld4(att_l + cb);
  const float K6 = 0.6f*1.44269504f, K4 = 0.4f*1.44269504f;
  h2 av6a = {(_Float16)(av.x*K6), (_Float16)(av.y*K6)};
  h2 av6b = {(_Float16)(av.z*K6), (_Float16)(av.w*K6)};
  h2 av4a = {(_Float16)(av.x*K4), (_Float16)(av.y*K4)};
  h2 av4b = {(_Float16)(av.z*K4), (_Float16)(av.w*K4)};

  float den = 0.f;
  float ax=0.f, ay=0.f, az=0.f, aw=0.f;

  int beg = rowp[d], stop = rowp[d+1];
  int i = beg;
  for (; i + 4 <= stop; i += 4){
    int p0 = csrp[i], p1 = csrp[i+1], p2 = csrp[i+2], p3 = csrp[i+3];
    uint2 u0 = *(const uint2*)(xlr + ((size_t)(p0 & 0xFFFF) << 9) + cb);
    uint2 u1 = *(const uint2*)(xlr + ((size_t)(p1 & 0xFFFF) << 9) + cb);
    uint2 u2 = *(const uint2*)(xlr + ((size_t)(p2 & 0xFFFF) << 9) + cb);
    uint2 u3 = *(const uint2*)(xlr + ((size_t)(p3 & 0xFFFF) << 9) + cb);
    int a0 = p0 >> 16, a1 = p1 >> 16, a2 = p2 >> 16, a3 = p3 >> 16;
    EDGE_BODY(u0.x, u0.y, a0);
    EDGE_BODY(u1.x, u1.y, a1);
    EDGE_BODY(u2.x, u2.y, a2);
    EDGE_BODY(u3.x, u3.y, a3);
  }
  if (i + 2 <= stop){
    int p0 = csrp[i], p1 = csrp[i+1];
    uint2 u0 = *(const uint2*)(xlr + ((size_t)(p0 & 0xFFFF) << 9) + cb);
    uint2 u1 = *(const uint2*)(xlr + ((size_t)(p1 & 0xFFFF) << 9) + cb);
    int a0 = p0 >> 16, a1 = p1 >> 16;
    EDGE_BODY(u0.x, u0.y, a0);
    EDGE_BODY(u1.x, u1.y, a1);
    i += 2;
  }
  if (i < stop){
    int p0 = csrp[i];
    uint2 u0 = *(const uint2*)(xlr + ((size_t)(p0 & 0xFFFF) << 9) + cb);
    int a0 = p0 >> 16;
    EDGE_BODY(u0.x, u0.y, a0);
  }

  float inv = (den > 0.f) ? 1.f/den : 0.f;
  ax *= inv; ay *= inv; az *= inv; aw *= inv;

  ax += __shfl_xor(ax,16); ay += __shfl_xor(ay,16); az += __shfl_xor(az,16); aw += __shfl_xor(aw,16);
  ax += __shfl_xor(ax,32); ay += __shfl_xor(ay,32); az += __shfl_xor(az,32); aw += __shfl_xor(aw,32);

  int cc = (lane & 15) << 2;
  float4 bv = ld4(bias_l + cc);
  float h0 = ax*0.25f + bv.x;
  float h1 = ay*0.25f + bv.y;
  float h2v = az*0.25f + bv.z;
  float h3 = aw*0.25f + bv.w;

  float s1 = h0+h1+h2v+h3;
  float s2 = h0*h0 + h1*h1 + h2v*h2v + h3*h3;
  s1 += __shfl_xor(s1,1); s2 += __shfl_xor(s2,1);
  s1 += __shfl_xor(s1,2); s2 += __shfl_xor(s2,2);
  s1 += __shfl_xor(s1,4); s2 += __shfl_xor(s2,4);
  s1 += __shfl_xor(s1,8); s2 += __shfl_xor(s2,8);
  float mu  = s1 * (1.f/64.f);
  float var = fmaxf(s2*(1.f/64.f) - mu*mu, 0.f);
  float rstd = rsqrtf(var + 1e-5f);
  float4 gv  = ld4(g_l + cc);
  float4 bbv = ld4(b_l + cc);
  float r0 = (h0-mu)*rstd*gv.x + bbv.x;
  float r1 = (h1-mu)*rstd*gv.y + bbv.y;
  float r2 = (h2v-mu)*rstd*gv.z + bbv.z;
  float r3 = (h3-mu)*rstd*gv.w + bbv.w;
  if (use_res){
    float4 hv = ld4(h_in + (size_t)d*HID + cc);
    r0 += hv.x; r1 += hv.y; r2 += hv.z; r3 += hv.w;
  }
  if (do_relu){
    r0 = fmaxf(r0, 0.f); r1 = fmaxf(r1, 0.f);
    r2 = fmaxf(r2, 0.f); r3 = fmaxf(r3, 0.f);
  }
  if (lane < 16){
    float4 o = {r0, r1, r2, r3};
    *(float4*)(h_out + (size_t)d*HID + cc) = o;
    ushort4 obv = {f2b(r0), f2b(r1), f2b(r2), f2b(r3)};
    *(ushort4*)(hbf + (size_t)d*HID + cc) = obv;
  }
}

// ---------------- launch ----------------
extern "C" void kernel_launch(void* const* d_in, const int* in_sizes, int n_in,
                              void* d_out, int out_size, void* d_ws, size_t ws_size,
                              hipStream_t stream){
  const float* x    = (const float*)d_in[0];
  const int*   ei   = (const int*)d_in[1];
  const int*   ea   = (const int*)d_in[2];
  const float* inW  = (const float*)d_in[3];
  const float* inb  = (const float*)d_in[4];
  const float* etab = (const float*)d_in[5];
  const float* Wl   = (const float*)d_in[6];
  const float* bl   = (const float*)d_in[7];
  const float* Wr   = (const float*)d_in[8];
  const float* br   = (const float*)d_in[9];
  const float* We   = (const float*)d_in[10];
  const float* att  = (const float*)d_in[11];
  const float* ob   = (const float*)d_in[12];
  const float* lg   = (const float*)d_in[13];
  const float* lb   = (const float*)d_in[14];

  char* w = (char*)d_ws;
  size_t off = 0;
  auto alloc = [&](size_t bytes)->char*{
    char* p = w + off;
    off = (off + bytes + 255) & ~(size_t)255;
    return p;
  };
  float* hA    = (float*)alloc((size_t)NN*HID*4);
  float* hB    = (float*)alloc((size_t)NN*HID*4);
  unsigned short* hbf = (unsigned short*)alloc((size_t)NN*HID*2);
  unsigned short* xlr = (unsigned short*)alloc((size_t)NN*512*2);
  unsigned short* inW_bf = (unsigned short*)alloc((size_t)HID*INDIM*2);
  unsigned short* Wlr    = (unsigned short*)alloc((size_t)NL*512*HID*2);
  float* blr   = (float*)alloc((size_t)NL*512*4);
  float* ep    = (float*)alloc((size_t)NL*3*HC*4);
  int*   deg   = (int*)alloc((size_t)NN*4);
  int*   bsum  = (int*)alloc((size_t)SCAN_NB*4);
  int*   rowp  = (int*)alloc((size_t)(NN+1)*4);
  int*   csrp  = (int*)alloc((size_t)NE*4);

  hipMemsetAsync(deg, 0, (size_t)NN*4, stream);

  const int* srcp = ei;
  const int* dstp = ei + NE;
  deg_kernel<<<dim3((NE+255)/256), dim3(256), 0, stream>>>(dstp, deg);
  scanA_kernel<<<dim3(SCAN_NB), dim3(256), 0, stream>>>(deg, bsum);
  scanB_kernel<<<dim3(1), dim3(256), 0, stream>>>(bsum);
  scanC_kernel<<<dim3(SCAN_NB), dim3(256), 0, stream>>>(deg, bsum, rowp);
  scatter_kernel<<<dim3((NE+255)/256), dim3(256), 0, stream>>>(srcp, dstp, ea, rowp, deg, csrp);
  prep_kernel<<<dim3(64), dim3(256), 0, stream>>>(inW, Wl, Wr, bl, br, etab, We, inW_bf, Wlr, blr, ep);

  const int MB = (NN + 127)/128;   // 391
  gemm_in_kernel<<<dim3(MB), dim3(256), 0, stream>>>(x, inW_bf, inb, hA, hbf);

  float* hcur = hA; float* hnext = hB;
  for (int l=0; l<NL; l++){
    gemm_lr_kernel<<<dim3(MB,8), dim3(256), 0, stream>>>(
        hbf, Wlr + (size_t)l*512*HID, blr + (size_t)l*512, xlr);
    float* hout = (l == NL-1) ? (float*)d_out : hnext;
    agg_kernel<<<dim3((NN+3)/4), dim3(256), 0, stream>>>(
        xlr, rowp, csrp,
        ep + (size_t)l*3*HC, att + (size_t)l*HC,
        ob + (size_t)l*HID, lg + (size_t)l*HID, lb + (size_t)l*HID,
        hcur, hout, hbf, (l >= NL/2) ? 1 : 0, (l < NL-1) ? 1 : 0);
    float* t = hcur; hcur = hnext; hnext = t;
  }
}

// Round 9
// 544.866 us; speedup vs baseline: 1.8015x; 1.0232x over previous
//
#include <hip/hip_runtime.h>
#include <hip/hip_bf16.h>
#include <hip/hip_fp16.h>
#include <math.h>

#define NN 50000
#define NE 400000
#define INDIM 128
#define HID 64
#define HC 256
#define NL 6
#define ED 16
#define SCAN_B 256
#define SCAN_NB ((NN + SCAN_B - 1)/SCAN_B)   // 196

typedef __attribute__((ext_vector_type(8))) short short8;
typedef __attribute__((ext_vector_type(4))) float f32x4;
typedef _Float16 h2 __attribute__((ext_vector_type(2)));

static __device__ __forceinline__ float4 ld4(const float* p){ return *(const float4*)p; }
static __device__ __forceinline__ unsigned short f2b(float x){
  __hip_bfloat16 h = __float2bfloat16(x);
  return *(unsigned short*)&h;
}
static __device__ __forceinline__ unsigned short f2h(float x){
  __half h = __float2half(x);
  return *(unsigned short*)&h;
}

// DPP-based lane combine: x + x[lane mapped by CTRL], pure VALU (no DS pipe).
// CTRL: 0xB1 = quad_perm(1,0,3,2) (xor1), 0x4E = quad_perm(2,3,0,1) (xor2),
//       0x124 = row_ror:4, 0x128 = row_ror:8 (within 16-lane row)
#define DPP_ADD(X, CTRL) \
  ((X) + __builtin_bit_cast(float, __builtin_amdgcn_update_dpp(0, __builtin_bit_cast(int, (X)), (CTRL), 0xF, 0xF, true)))

// ---------------- prep: bf16 weights + Wl/Wr fusion + ep_table ----------------
__global__ void prep_kernel(const float* __restrict__ inW, const float* __restrict__ Wl,
                            const float* __restrict__ Wr, const float* __restrict__ bl,
                            const float* __restrict__ br, const float* __restrict__ etab,
                            const float* __restrict__ We,
                            unsigned short* __restrict__ inW_bf,
                            unsigned short* __restrict__ Wlr,
                            float* __restrict__ blr, float* __restrict__ ep){
  int i = blockIdx.x*blockDim.x + threadIdx.x;
  if (i < HID*INDIM) inW_bf[i] = f2b(inW[i]);
  if (i < NL*512){
    int l = i / 512, c = i % 512;
    blr[i] = (c < HC) ? bl[l*HC + c] : br[l*HC + (c-HC)];
  }
  if (i < NL*3*HC){
    int l  = i / (3*HC);
    int a  = (i / HC) % 3;
    int hc = i % HC;
    const float* wrow = We + ((size_t)l*HC + hc)*ED;
    const float* erow = etab + a*ED;
    float s = 0.f;
    #pragma unroll
    for (int k=0;k<ED;k++) s += erow[k]*wrow[k];
    ep[i] = s;
  }
  int tot = NL*512*HID;
  for (int j = i; j < tot; j += gridDim.x*blockDim.x){
    int l = j / (512*HID);
    int c = (j / HID) % 512;
    int k = j % HID;
    float v = (c < HC) ? Wl[((size_t)l*HC + c)*HID + k]
                       : Wr[((size_t)l*HC + (c-HC))*HID + k];
    Wlr[j] = f2b(v);
  }
}

// ---------------- CSR build ----------------
__global__ void deg_kernel(const int* __restrict__ dst, int* __restrict__ deg){
  int e = blockIdx.x*blockDim.x + threadIdx.x;
  if (e < NE) atomicAdd(&deg[dst[e]], 1);
}

__global__ void scanA_kernel(const int* __restrict__ deg, int* __restrict__ bsum){
  int t = threadIdx.x;
  int i = blockIdx.x*SCAN_B + t;
  int v = (i < NN) ? deg[i] : 0;
  #pragma unroll
  for (int o=1;o<64;o<<=1) v += __shfl_xor(v,o);
  __shared__ int ws[4];
  if ((t&63)==0) ws[t>>6] = v;
  __syncthreads();
  if (t==0) bsum[blockIdx.x] = ws[0]+ws[1]+ws[2]+ws[3];
}

__global__ void scanB_kernel(int* __restrict__ bsum){
  __shared__ int sh[256];
  int t = threadIdx.x;
  int v = (t < SCAN_NB) ? bsum[t] : 0;
  sh[t] = v;
  __syncthreads();
  for (int o=1;o<256;o<<=1){
    int u = (t>=o)?sh[t-o]:0;
    __syncthreads();
    sh[t]+=u;
    __syncthreads();
  }
  int excl = (t==0)?0:sh[t-1];
  if (t < SCAN_NB) bsum[t] = excl;
}

__global__ void scanC_kernel(const int* __restrict__ deg, const int* __restrict__ bsum,
                             int* __restrict__ rowp){
  int t = threadIdx.x, b = blockIdx.x;
  int i = b*SCAN_B + t;
  int v = (i<NN)?deg[i]:0;
  __shared__ int sh[256];
  sh[t]=v;
  __syncthreads();
  for (int o=1;o<256;o<<=1){
    int u=(t>=o)?sh[t-o]:0;
    __syncthreads();
    sh[t]+=u;
    __syncthreads();
  }
  if (i < NN) rowp[i] = bsum[b] + sh[t] - v;
  if (i == 0) rowp[NN] = NE;
}

// scatter packed (src | attr<<16); consumes deg as a countdown counter
__global__ void scatter_kernel(const int* __restrict__ src, const int* __restrict__ dst,
                               const int* __restrict__ attr, const int* __restrict__ rowp,
                               int* __restrict__ deg, int* __restrict__ csrp){
  int e = blockIdx.x*blockDim.x + threadIdx.x;
  if (e >= NE) return;
  int d = dst[e];
  int pos = rowp[d] + atomicSub(&deg[d], 1) - 1;
  csrp[pos] = src[e] | (attr[e] << 16);
}

// ---------------- input GEMM: h = x @ inW.T + b ----------------
__global__ __launch_bounds__(256) void gemm_in_kernel(
    const float* __restrict__ X, const unsigned short* __restrict__ Wbf,
    const float* __restrict__ bias, float* __restrict__ hout, unsigned short* __restrict__ hbf)
{
  int wid = threadIdx.x >> 6, lane = threadIdx.x & 63;
  int row0 = blockIdx.x*128 + wid*32;
  int lr = lane & 15, lk = lane >> 4;
  short8 a[2][4];
  #pragma unroll
  for (int rt=0; rt<2; rt++){
    int r = row0 + rt*16 + lr; if (r >= NN) r = NN-1;
    const float* rp = X + (size_t)r*INDIM;
    #pragma unroll
    for (int ks=0; ks<4; ks++){
      const float* p = rp + ks*32 + lk*8;
      float4 u = ld4(p), v = ld4(p+4);
      short8 t;
      t[0]=(short)f2b(u.x); t[1]=(short)f2b(u.y); t[2]=(short)f2b(u.z); t[3]=(short)f2b(u.w);
      t[4]=(short)f2b(v.x); t[5]=(short)f2b(v.y); t[6]=(short)f2b(v.z); t[7]=(short)f2b(v.w);
      a[rt][ks] = t;
    }
  }
  f32x4 acc[2][4] = {};
  #pragma unroll
  for (int ct=0; ct<4; ct++){
    int c = ct*16 + lr;
    #pragma unroll
    for (int ks=0; ks<4; ks++){
      short8 b = *(const short8*)&Wbf[(size_t)c*INDIM + ks*32 + lk*8];
      #pragma unroll
      for (int rt=0; rt<2; rt++)
        acc[rt][ct] = __builtin_amdgcn_mfma_f32_16x16x32_bf16(a[rt][ks], b, acc[rt][ct], 0,0,0);
    }
  }
  #pragma unroll
  for (int rt=0; rt<2; rt++)
    #pragma unroll
    for (int ct=0; ct<4; ct++){
      int c = ct*16 + lr;
      float bv = bias[c];
      #pragma unroll
      for (int q=0;q<4;q++){
        int r = row0 + rt*16 + lk*4 + q;
        if (r < NN){
          float v = acc[rt][ct][q] + bv;
          hout[(size_t)r*HID + c] = v;
          hbf[(size_t)r*HID + c] = f2b(v);
        }
      }
    }
}

// ---------------- layer GEMM: xlr = h_bf @ Wlr.T + blr ([NN][512] fp16) ----------------
__global__ __launch_bounds__(256) void gemm_lr_kernel(
    const unsigned short* __restrict__ Abf, const unsigned short* __restrict__ Wbf,
    const float* __restrict__ bias, unsigned short* __restrict__ out)
{
  int wid = threadIdx.x >> 6, lane = threadIdx.x & 63;
  int row0 = blockIdx.x*128 + wid*32;
  int col0 = blockIdx.y*64;
  int lr = lane & 15, lk = lane >> 4;
  short8 a[2][2];
  #pragma unroll
  for (int rt=0; rt<2; rt++){
    int r = row0 + rt*16 + lr; if (r >= NN) r = NN-1;
    #pragma unroll
    for (int ks=0; ks<2; ks++)
      a[rt][ks] = *(const short8*)&Abf[(size_t)r*HID + ks*32 + lk*8];
  }
  f32x4 acc[2][4] = {};
  #pragma unroll
  for (int ct=0; ct<4; ct++){
    int c = col0 + ct*16 + lr;
    #pragma unroll
    for (int ks=0; ks<2; ks++){
      short8 b = *(const short8*)&Wbf[(size_t)c*HID + ks*32 + lk*8];
      #pragma unroll
      for (int rt=0; rt<2; rt++)
        acc[rt][ct] = __builtin_amdgcn_mfma_f32_16x16x32_bf16(a[rt][ks], b, acc[rt][ct], 0,0,0);
    }
  }
  #pragma unroll
  for (int rt=0; rt<2; rt++)
    #pragma unroll
    for (int ct=0; ct<4; ct++){
      int c = col0 + ct*16 + lr;
      float bv = bias[c];
      #pragma unroll
      for (int q=0;q<4;q++){
        int r = row0 + rt*16 + lk*4 + q;
        if (r < NN) out[(size_t)r*512 + c] = f2h(acc[rt][ct][q] + bv);
      }
    }
}

// ---------------- fused GATv2 aggregation + head-mean + LN + residual + relu ----------------
// one wave per dst node; lane holds 4 channels of [H=4][C=64]; xlr fp16 [NN][512]
// round-9: 16-lane logit reduce via DPP (quad_perm xor1, xor2, row_ror:4, row_ror:8)
//          — removes 4 ds_bpermute ops per edge from the critical chain
#define EDGE_BODY(UX, UY, A)                                                   \
  {                                                                            \
    h2 x2a = __builtin_bit_cast(h2, (UX));                                     \
    h2 x2b = __builtin_bit_cast(h2, (UY));                                     \
    h2 m2a = x2a + ((A)==0 ? xre0a : ((A)==1 ? xre1a : xre2a));                \
    h2 m2b = x2b + ((A)==0 ? xre0b : ((A)==1 ? xre1b : xre2b));                \
    h2 n2a = __builtin_bit_cast(h2, __builtin_bit_cast(unsigned, m2a) & 0x7FFF7FFFu); \
    h2 n2b = __builtin_bit_cast(h2, __builtin_bit_cast(unsigned, m2b) & 0x7FFF7FFFu); \
    float part = __builtin_amdgcn_fdot2(m2a, av6a, 0.f, false);                \
    part = __builtin_amdgcn_fdot2(m2b, av6b, part, false);                     \
    part = __builtin_amdgcn_fdot2(n2a, av4a, part, false);                     \
    part = __builtin_amdgcn_fdot2(n2b, av4b, part, false);                     \
    part = DPP_ADD(part, 0xB1);                                                \
    part = DPP_ADD(part, 0x4E);                                                \
    part = DPP_ADD(part, 0x124);                                               \
    part = DPP_ADD(part, 0x128);                                               \
    float p = exp2f(part);                                                     \
    den += p;                                                                  \
    ax = fmaf(p, (float)x2a.x, ax);                                            \
    ay = fmaf(p, (float)x2a.y, ay);                                            \
    az = fmaf(p, (float)x2b.x, az);                                            \
    aw = fmaf(p, (float)x2b.y, aw);                                            \
  }

__global__ __launch_bounds__(256) void agg_kernel(
    const unsigned short* __restrict__ xlr,
    const int* __restrict__ rowp, const int* __restrict__ csrp,
    const float* __restrict__ ep_l, const float* __restrict__ att_l,
    const float* __restrict__ bias_l, const float* __restrict__ g_l, const float* __restrict__ b_l,
    const float* __restrict__ h_in, float* __restrict__ h_out, unsigned short* __restrict__ hbf,
    int use_res, int do_relu)
{
  int d = (blockIdx.x << 2) | (threadIdx.x >> 6);
  int lane = threadIdx.x & 63;
  if (d >= NN) return;
  int cb = lane << 2;

  uint2 xru = *(const uint2*)(xlr + ((size_t)d << 9) + 256 + cb);
  h2 xr2a = __builtin_bit_cast(h2, xru.x);
  h2 xr2b = __builtin_bit_cast(h2, xru.y);
  float xrf0 = (float)xr2a.x, xrf1 = (float)xr2a.y;
  float xrf2 = (float)xr2b.x, xrf3 = (float)xr2b.y;

  float4 ev0 = ld4(ep_l + cb);
  float4 ev1 = ld4(ep_l + HC + cb);
  float4 ev2 = ld4(ep_l + 2*HC + cb);
  h2 xre0a = {(_Float16)(xrf0+ev0.x), (_Float16)(xrf1+ev0.y)};
  h2 xre0b = {(_Float16)(xrf2+ev0.z), (_Float16)(xrf3+ev0.w)};
  h2 xre1a = {(_Float16)(xrf0+ev1.x), (_Float16)(xrf1+ev1.y)};
  h2 xre1b = {(_Float16)(xrf2+ev1.z), (_Float16)(xrf3+ev1.w)};
  h2 xre2a = {(_Float16)(xrf0+ev2.x), (_Float16)(xrf1+ev2.y)};
  h2 xre2b = {(_Float16)(xrf2+ev2.z), (_Float16)(xrf3+ev2.w)};

  float4 av = ld4(att_l + cb);
  const float K6 = 0.6f*1.44269504f, K4 = 0.4f*1.44269504f;
  h2 av6a = {(_Float16)(av.x*K6), (_Float16)(av.y*K6)};
  h2 av6b = {(_Float16)(av.z*K6), (_Float16)(av.w*K6)};
  h2 av4a = {(_Float16)(av.x*K4), (_Float16)(av.y*K4)};
  h2 av4b = {(_Float16)(av.z*K4), (_Float16)(av.w*K4)};

  float den = 0.f;
  float ax=0.f, ay=0.f, az=0.f, aw=0.f;

  int beg = rowp[d], stop = rowp[d+1];
  int i = beg;
  for (; i + 4 <= stop; i += 4){
    int p0 = csrp[i], p1 = csrp[i+1], p2 = csrp[i+2], p3 = csrp[i+3];
    uint2 u0 = *(const uint2*)(xlr + ((size_t)(p0 & 0xFFFF) << 9) + cb);
    uint2 u1 = *(const uint2*)(xlr + ((size_t)(p1 & 0xFFFF) << 9) + cb);
    uint2 u2 = *(const uint2*)(xlr + ((size_t)(p2 & 0xFFFF) << 9) + cb);
    uint2 u3 = *(const uint2*)(xlr + ((size_t)(p3 & 0xFFFF) << 9) + cb);
    int a0 = p0 >> 16, a1 = p1 >> 16, a2 = p2 >> 16, a3 = p3 >> 16;
    EDGE_BODY(u0.x, u0.y, a0);
    EDGE_BODY(u1.x, u1.y, a1);
    EDGE_BODY(u2.x, u2.y, a2);
    EDGE_BODY(u3.x, u3.y, a3);
  }
  if (i + 2 <= stop){
    int p0 = csrp[i], p1 = csrp[i+1];
    uint2 u0 = *(const uint2*)(xlr + ((size_t)(p0 & 0xFFFF) << 9) + cb);
    uint2 u1 = *(const uint2*)(xlr + ((size_t)(p1 & 0xFFFF) << 9) + cb);
    int a0 = p0 >> 16, a1 = p1 >> 16;
    EDGE_BODY(u0.x, u0.y, a0);
    EDGE_BODY(u1.x, u1.y, a1);
    i += 2;
  }
  if (i < stop){
    int p0 = csrp[i];
    uint2 u0 = *(const uint2*)(xlr + ((size_t)(p0 & 0xFFFF) << 9) + cb);
    int a0 = p0 >> 16;
    EDGE_BODY(u0.x, u0.y, a0);
  }

  float inv = (den > 0.f) ? 1.f/den : 0.f;
  ax *= inv; ay *= inv; az *= inv; aw *= inv;

  ax += __shfl_xor(ax,16); ay += __shfl_xor(ay,16); az += __shfl_xor(az,16); aw += __shfl_xor(aw,16);
  ax += __shfl_xor(ax,32); ay += __shfl_xor(ay,32); az += __shfl_xor(az,32); aw += __shfl_xor(aw,32);

  int cc = (lane & 15) << 2;
  float4 bv = ld4(bias_l + cc);
  float h0 = ax*0.25f + bv.x;
  float h1 = ay*0.25f + bv.y;
  float h2v = az*0.25f + bv.z;
  float h3 = aw*0.25f + bv.w;

  float s1 = h0+h1+h2v+h3;
  float s2 = h0*h0 + h1*h1 + h2v*h2v + h3*h3;
  s1 += __shfl_xor(s1,1); s2 += __shfl_xor(s2,1);
  s1 += __shfl_xor(s1,2); s2 += __shfl_xor(s2,2);
  s1 += __shfl_xor(s1,4); s2 += __shfl_xor(s2,4);
  s1 += __shfl_xor(s1,8); s2 += __shfl_xor(s2,8);
  float mu  = s1 * (1.f/64.f);
  float var = fmaxf(s2*(1.f/64.f) - mu*mu, 0.f);
  float rstd = rsqrtf(var + 1e-5f);
  float4 gv  = ld4(g_l + cc);
  float4 bbv = ld4(b_l + cc);
  float r0 = (h0-mu)*rstd*gv.x + bbv.x;
  float r1 = (h1-mu)*rstd*gv.y + bbv.y;
  float r2 = (h2v-mu)*rstd*gv.z + bbv.z;
  float r3 = (h3-mu)*rstd*gv.w + bbv.w;
  if (use_res){
    float4 hv = ld4(h_in + (size_t)d*HID + cc);
    r0 += hv.x; r1 += hv.y; r2 += hv.z; r3 += hv.w;
  }
  if (do_relu){
    r0 = fmaxf(r0, 0.f); r1 = fmaxf(r1, 0.f);
    r2 = fmaxf(r2, 0.f); r3 = fmaxf(r3, 0.f);
  }
  if (lane < 16){
    float4 o = {r0, r1, r2, r3};
    *(float4*)(h_out + (size_t)d*HID + cc) = o;
    ushort4 obv = {f2b(r0), f2b(r1), f2b(r2), f2b(r3)};
    *(ushort4*)(hbf + (size_t)d*HID + cc) = obv;
  }
}

// ---------------- launch ----------------
extern "C" void kernel_launch(void* const* d_in, const int* in_sizes, int n_in,
                              void* d_out, int out_size, void* d_ws, size_t ws_size,
                              hipStream_t stream){
  const float* x    = (const float*)d_in[0];
  const int*   ei   = (const int*)d_in[1];
  const int*   ea   = (const int*)d_in[2];
  const float* inW  = (const float*)d_in[3];
  const float* inb  = (const float*)d_in[4];
  const float* etab = (const float*)d_in[5];
  const float* Wl   = (const float*)d_in[6];
  const float* bl   = (const float*)d_in[7];
  const float* Wr   = (const float*)d_in[8];
  const float* br   = (const float*)d_in[9];
  const float* We   = (const float*)d_in[10];
  const float* att  = (const float*)d_in[11];
  const float* ob   = (const float*)d_in[12];
  const float* lg   = (const float*)d_in[13];
  const float* lb   = (const float*)d_in[14];

  char* w = (char*)d_ws;
  size_t off = 0;
  auto alloc = [&](size_t bytes)->char*{
    char* p = w + off;
    off = (off + bytes + 255) & ~(size_t)255;
    return p;
  };
  float* hA    = (float*)alloc((size_t)NN*HID*4);
  float* hB    = (float*)alloc((size_t)NN*HID*4);
  unsigned short* hbf = (unsigned short*)alloc((size_t)NN*HID*2);
  unsigned short* xlr = (unsigned short*)alloc((size_t)NN*512*2);
  unsigned short* inW_bf = (unsigned short*)alloc((size_t)HID*INDIM*2);
  unsigned short* Wlr    = (unsigned short*)alloc((size_t)NL*512*HID*2);
  float* blr   = (float*)alloc((size_t)NL*512*4);
  float* ep    = (float*)alloc((size_t)NL*3*HC*4);
  int*   deg   = (int*)alloc((size_t)NN*4);
  int*   bsum  = (int*)alloc((size_t)SCAN_NB*4);
  int*   rowp  = (int*)alloc((size_t)(NN+1)*4);
  int*   csrp  = (int*)alloc((size_t)NE*4);

  hipMemsetAsync(deg, 0, (size_t)NN*4, stream);

  const int* srcp = ei;
  const int* dstp = ei + NE;
  deg_kernel<<<dim3((NE+255)/256), dim3(256), 0, stream>>>(dstp, deg);
  scanA_kernel<<<dim3(SCAN_NB), dim3(256), 0, stream>>>(deg, bsum);
  scanB_kernel<<<dim3(1), dim3(256), 0, stream>>>(bsum);
  scanC_kernel<<<dim3(SCAN_NB), dim3(256), 0, stream>>>(deg, bsum, rowp);
  scatter_kernel<<<dim3((NE+255)/256), dim3(256), 0, stream>>>(srcp, dstp, ea, rowp, deg, csrp);
  prep_kernel<<<dim3(64), dim3(256), 0, stream>>>(inW, Wl, Wr, bl, br, etab, We, inW_bf, Wlr, blr, ep);

  const int MB = (NN + 127)/128;   // 391
  gemm_in_kernel<<<dim3(MB), dim3(256), 0, stream>>>(x, inW_bf, inb, hA, hbf);

  float* hcur = hA; float* hnext = hB;
  for (int l=0; l<NL; l++){
    gemm_lr_kernel<<<dim3(MB,8), dim3(256), 0, stream>>>(
        hbf, Wlr + (size_t)l*512*HID, blr + (size_t)l*512, xlr);
    float* hout = (l == NL-1) ? (float*)d_out : hnext;
    agg_kernel<<<dim3((NN+3)/4), dim3(256), 0, stream>>>(
        xlr, rowp, csrp,
        ep + (size_t)l*3*HC, att + (size_t)l*HC,
        ob + (size_t)l*HID, lg + (size_t)l*HID, lb + (size_t)l*HID,
        hcur, hout, hbf, (l >= NL/2) ? 1 : 0, (l < NL-1) ? 1 : 0);
    float* t = hcur; hcur = hnext; hnext = t;
  }
}